// Round 1
// baseline (2103.844 us; speedup 1.0000x reference)
//
#include <hip/hip_runtime.h>
#include <hip/hip_bf16.h>

typedef __hip_bfloat16 bf16;

#define NS 256      // N_SEQ
#define NR 256      // N_RES
#define CM 256      // C_M
#define CZ 128      // C_Z
#define NH 8        // heads
#define CH 32       // head dim
#define LN_EPS 1e-5f

// ---------------------------------------------------------------------------
// Kernel 1: LayerNorm over m's channel dim, output bf16
// grid = NS*NR blocks, 256 threads (one per channel)
// ---------------------------------------------------------------------------
__global__ __launch_bounds__(256) void ln_m_kernel(
    const float* __restrict__ m, const float* __restrict__ w,
    const float* __restrict__ b, bf16* __restrict__ mn) {
  int row = blockIdx.x;
  int t = threadIdx.x;
  __shared__ float red[4];

  float x = m[(size_t)row * CM + t];

  float v = x;
  #pragma unroll
  for (int off = 32; off; off >>= 1) v += __shfl_xor(v, off);
  if ((t & 63) == 0) red[t >> 6] = v;
  __syncthreads();
  float mu = (red[0] + red[1] + red[2] + red[3]) * (1.0f / CM);
  float d = x - mu;
  __syncthreads();

  v = d * d;
  #pragma unroll
  for (int off = 32; off; off >>= 1) v += __shfl_xor(v, off);
  if ((t & 63) == 0) red[t >> 6] = v;
  __syncthreads();
  float var = (red[0] + red[1] + red[2] + red[3]) * (1.0f / CM);

  float y = d * rsqrtf(var + LN_EPS) * w[t] + b[t];
  mn[(size_t)row * CM + t] = __float2bfloat16(y);
}

// ---------------------------------------------------------------------------
// Kernel 2: bias[h][i][j] = (LN(z[i,j,:]) @ w_z)[h]
// grid = NR*NR blocks, 128 threads
// ---------------------------------------------------------------------------
__global__ __launch_bounds__(128) void bias_kernel(
    const float* __restrict__ z, const float* __restrict__ w,
    const float* __restrict__ b, const float* __restrict__ wz,
    float* __restrict__ bias) {
  int row = blockIdx.x;   // i*NR + j
  int t = threadIdx.x;    // 0..127
  __shared__ float red[2];
  __shared__ float zn[CZ];

  float x = z[(size_t)row * CZ + t];

  float v = x;
  #pragma unroll
  for (int off = 32; off; off >>= 1) v += __shfl_xor(v, off);
  if ((t & 63) == 0) red[t >> 6] = v;
  __syncthreads();
  float mu = (red[0] + red[1]) * (1.0f / CZ);
  float d = x - mu;
  __syncthreads();

  v = d * d;
  #pragma unroll
  for (int off = 32; off; off >>= 1) v += __shfl_xor(v, off);
  if ((t & 63) == 0) red[t >> 6] = v;
  __syncthreads();
  float var = (red[0] + red[1]) * (1.0f / CZ);

  zn[t] = d * rsqrtf(var + LN_EPS) * w[t] + b[t];
  __syncthreads();

  if (t < NH) {
    float acc = 0.0f;
    #pragma unroll 8
    for (int c = 0; c < CZ; ++c) acc += zn[c] * wz[c * NH + t];
    bias[(size_t)t * (NR * NR) + row] = acc;
  }
}

// ---------------------------------------------------------------------------
// Kernel 3: fused q/k/v/g projections. 8 rows per block, 256 threads.
// q = mn@w_q, k = mn@w_k, v = mn@w_v, g = sigmoid(mn@w_g + b_g); all bf16 out
// ---------------------------------------------------------------------------
__global__ __launch_bounds__(256) void qkvg_kernel(
    const bf16* __restrict__ mn,
    const float* __restrict__ wq, const float* __restrict__ wk,
    const float* __restrict__ wv, const float* __restrict__ wg,
    const float* __restrict__ bg,
    bf16* __restrict__ qo, bf16* __restrict__ ko,
    bf16* __restrict__ vo, bf16* __restrict__ go) {
  int r0 = blockIdx.x * 8;
  int t = threadIdx.x;
  __shared__ float mrow[8][CM];

  #pragma unroll
  for (int r = 0; r < 8; ++r)
    mrow[r][t] = __bfloat162float(mn[(size_t)(r0 + r) * CM + t]);
  __syncthreads();

  float aq[8] = {}, ak[8] = {}, av[8] = {}, ag[8] = {};
  for (int kk = 0; kk < CM; ++kk) {
    float wqv = wq[kk * 256 + t];
    float wkv = wk[kk * 256 + t];
    float wvv = wv[kk * 256 + t];
    float wgv = wg[kk * 256 + t];
    #pragma unroll
    for (int r = 0; r < 8; ++r) {
      float mv = mrow[r][kk];
      aq[r] = fmaf(mv, wqv, aq[r]);
      ak[r] = fmaf(mv, wkv, ak[r]);
      av[r] = fmaf(mv, wvv, av[r]);
      ag[r] = fmaf(mv, wgv, ag[r]);
    }
  }

  float bgv = bg[t];
  #pragma unroll
  for (int r = 0; r < 8; ++r) {
    size_t idx = (size_t)(r0 + r) * 256 + t;
    qo[idx] = __float2bfloat16(aq[r]);
    ko[idx] = __float2bfloat16(ak[r]);
    vo[idx] = __float2bfloat16(av[r]);
    float s = 1.0f / (1.0f + __expf(-(ag[r] + bgv)));
    go[idx] = __float2bfloat16(s);
  }
}

// ---------------------------------------------------------------------------
// Kernel 4: attention per (s, h). K rows in registers, V in padded LDS.
// For each q row: logits -> softmax -> o; write g*o (bf16).
// grid = NS*NH blocks, 256 threads (thread = k index)
// ---------------------------------------------------------------------------
__global__ __launch_bounds__(256) void attn_kernel(
    const bf16* __restrict__ qb, const bf16* __restrict__ kb,
    const bf16* __restrict__ vb, const bf16* __restrict__ gb,
    const float* __restrict__ bias, bf16* __restrict__ gob) {
  int sh = blockIdx.x;
  int s = sh >> 3, h = sh & 7;
  int t = threadIdx.x;  // k index
  const float scale = 0.17677669529663687f;  // 1/sqrt(32)

  __shared__ float Vs[NR][CH + 1];
  __shared__ float qs[CH];
  __shared__ float attn[NR];
  __shared__ float red8[8][CH];
  __shared__ float rbuf[4];

  // stage K row (registers) and V row (LDS)
  float kreg[CH];
  {
    const bf16* kp = kb + ((size_t)(s * NR + t)) * 256 + h * CH;
    const bf16* vp = vb + ((size_t)(s * NR + t)) * 256 + h * CH;
    #pragma unroll
    for (int d = 0; d < CH; ++d) {
      kreg[d] = __bfloat162float(kp[d]);
      Vs[t][d] = __bfloat162float(vp[d]);
    }
  }
  __syncthreads();

  const float* brow = bias + (size_t)h * (NR * NR);

  for (int qi = 0; qi < NR; ++qi) {
    if (t < CH)
      qs[t] = __bfloat162float(qb[((size_t)(s * NR + qi)) * 256 + h * CH + t]);
    __syncthreads();

    float acc = 0.0f;
    #pragma unroll
    for (int d = 0; d < CH; ++d) acc = fmaf(qs[d], kreg[d], acc);
    float logit = acc * scale + brow[qi * NR + t];

    // block max
    float v = logit;
    #pragma unroll
    for (int off = 32; off; off >>= 1) v = fmaxf(v, __shfl_xor(v, off));
    if ((t & 63) == 0) rbuf[t >> 6] = v;
    __syncthreads();
    float mx = fmaxf(fmaxf(rbuf[0], rbuf[1]), fmaxf(rbuf[2], rbuf[3]));
    float e = __expf(logit - mx);
    __syncthreads();

    // block sum
    v = e;
    #pragma unroll
    for (int off = 32; off; off >>= 1) v += __shfl_xor(v, off);
    if ((t & 63) == 0) rbuf[t >> 6] = v;
    __syncthreads();
    float se = rbuf[0] + rbuf[1] + rbuf[2] + rbuf[3];
    attn[t] = e / se;
    __syncthreads();

    // o[d] = sum_k attn[k] * V[k][d], split k over 8 groups
    int d = t & 31, kg = t >> 5;
    float oacc = 0.0f;
    #pragma unroll 8
    for (int k2 = kg; k2 < NR; k2 += 8) oacc = fmaf(attn[k2], Vs[k2][d], oacc);
    red8[kg][d] = oacc;
    __syncthreads();

    if (t < CH) {
      float o = 0.0f;
      #pragma unroll
      for (int j = 0; j < 8; ++j) o += red8[j][t];
      size_t idx = ((size_t)(s * NR + qi)) * 256 + h * CH + t;
      float gg = __bfloat162float(gb[idx]);
      gob[idx] = __float2bfloat16(gg * o);
    }
    __syncthreads();  // protect qs/attn/red8 for next iteration
  }
}

// ---------------------------------------------------------------------------
// Kernel 5: out = (g*o) @ w_o + b_o, f32 output. 8 rows per block.
// ---------------------------------------------------------------------------
__global__ __launch_bounds__(256) void out_kernel(
    const bf16* __restrict__ gob, const float* __restrict__ wo,
    const float* __restrict__ bo, float* __restrict__ out) {
  int r0 = blockIdx.x * 8;
  int t = threadIdx.x;
  __shared__ float grow[8][256];

  #pragma unroll
  for (int r = 0; r < 8; ++r)
    grow[r][t] = __bfloat162float(gob[(size_t)(r0 + r) * 256 + t]);
  __syncthreads();

  float acc[8] = {};
  for (int kk = 0; kk < 256; ++kk) {
    float wv = wo[kk * 256 + t];
    #pragma unroll
    for (int r = 0; r < 8; ++r) acc[r] = fmaf(grow[r][kk], wv, acc[r]);
  }

  float bv = bo[t];
  #pragma unroll
  for (int r = 0; r < 8; ++r)
    out[(size_t)(r0 + r) * 256 + t] = acc[r] + bv;
}

// ---------------------------------------------------------------------------
extern "C" void kernel_launch(void* const* d_in, const int* in_sizes, int n_in,
                              void* d_out, int out_size, void* d_ws, size_t ws_size,
                              hipStream_t stream) {
  const float* m      = (const float*)d_in[0];
  const float* z      = (const float*)d_in[1];
  const float* ln_m_w = (const float*)d_in[2];
  const float* ln_m_b = (const float*)d_in[3];
  const float* ln_z_w = (const float*)d_in[4];
  const float* ln_z_b = (const float*)d_in[5];
  const float* w_z    = (const float*)d_in[6];
  const float* w_q    = (const float*)d_in[7];
  const float* w_k    = (const float*)d_in[8];
  const float* w_v    = (const float*)d_in[9];
  const float* w_g    = (const float*)d_in[10];
  const float* b_g    = (const float*)d_in[11];
  const float* w_o    = (const float*)d_in[12];
  const float* b_o    = (const float*)d_in[13];
  float* out = (float*)d_out;

  const size_t SZ = (size_t)NS * NR * 256;  // 16,777,216 elements

  bf16* mn   = (bf16*)d_ws;
  bf16* qb   = mn + SZ;
  bf16* kb   = qb + SZ;
  bf16* vb   = kb + SZ;
  bf16* gb   = vb + SZ;
  bf16* gob  = gb + SZ;
  float* bias = (float*)(gob + SZ);  // NH*NR*NR floats = 2 MB

  ln_m_kernel<<<NS * NR, 256, 0, stream>>>(m, ln_m_w, ln_m_b, mn);
  bias_kernel<<<NR * NR, 128, 0, stream>>>(z, ln_z_w, ln_z_b, w_z, bias);
  qkvg_kernel<<<(NS * NR) / 8, 256, 0, stream>>>(mn, w_q, w_k, w_v, w_g, b_g,
                                                 qb, kb, vb, gb);
  attn_kernel<<<NS * NH, 256, 0, stream>>>(qb, kb, vb, gb, bias, gob);
  out_kernel<<<(NS * NR) / 8, 256, 0, stream>>>(gob, w_o, b_o, out);
}

// Round 2
// 987.243 us; speedup vs baseline: 2.1310x; 2.1310x over previous
//
#include <hip/hip_runtime.h>
#include <hip/hip_bf16.h>

typedef __hip_bfloat16 bf16;
typedef __attribute__((ext_vector_type(8))) short short8;
typedef __attribute__((ext_vector_type(16))) float f32x16;

#define NS 256      // N_SEQ
#define NR 256      // N_RES
#define CM 256      // C_M
#define CZ 128      // C_Z
#define NH 8        // heads
#define CH 32       // head dim
#define LN_EPS 1e-5f
#define LOG2E 1.4426950408889634f
// (1/sqrt(32)) * log2(e): fold into logits so exp == exp2
#define SCALE2 (0.17677669529663687f * 1.4426950408889634f)

__device__ __forceinline__ unsigned pk_bf16(float lo, float hi) {
  unsigned r;
  asm volatile("v_cvt_pk_bf16_f32 %0, %1, %2" : "=v"(r) : "v"(lo), "v"(hi));
  return r;
}

// ---------------------------------------------------------------------------
// Kernel 1: LayerNorm over m's channel dim, output bf16
// ---------------------------------------------------------------------------
__global__ __launch_bounds__(256) void ln_m_kernel(
    const float* __restrict__ m, const float* __restrict__ w,
    const float* __restrict__ b, bf16* __restrict__ mn) {
  int row = blockIdx.x;
  int t = threadIdx.x;
  __shared__ float red[4];

  float x = m[(size_t)row * CM + t];

  float v = x;
  #pragma unroll
  for (int off = 32; off; off >>= 1) v += __shfl_xor(v, off);
  if ((t & 63) == 0) red[t >> 6] = v;
  __syncthreads();
  float mu = (red[0] + red[1] + red[2] + red[3]) * (1.0f / CM);
  float d = x - mu;
  __syncthreads();

  v = d * d;
  #pragma unroll
  for (int off = 32; off; off >>= 1) v += __shfl_xor(v, off);
  if ((t & 63) == 0) red[t >> 6] = v;
  __syncthreads();
  float var = (red[0] + red[1] + red[2] + red[3]) * (1.0f / CM);

  float y = d * rsqrtf(var + LN_EPS) * w[t] + b[t];
  mn[(size_t)row * CM + t] = __float2bfloat16(y);
}

// ---------------------------------------------------------------------------
// Kernel 2: biasT[h][k][q] = (LN(z[q,k,:]) @ w_z)[h] * log2(e)   (transposed!)
// ---------------------------------------------------------------------------
__global__ __launch_bounds__(128) void bias_kernel(
    const float* __restrict__ z, const float* __restrict__ w,
    const float* __restrict__ b, const float* __restrict__ wz,
    float* __restrict__ biasT) {
  int row = blockIdx.x;   // i*NR + j  (i = q, j = k)
  int t = threadIdx.x;    // 0..127
  __shared__ float red[2];
  __shared__ float zn[CZ];

  float x = z[(size_t)row * CZ + t];

  float v = x;
  #pragma unroll
  for (int off = 32; off; off >>= 1) v += __shfl_xor(v, off);
  if ((t & 63) == 0) red[t >> 6] = v;
  __syncthreads();
  float mu = (red[0] + red[1]) * (1.0f / CZ);
  float d = x - mu;
  __syncthreads();

  v = d * d;
  #pragma unroll
  for (int off = 32; off; off >>= 1) v += __shfl_xor(v, off);
  if ((t & 63) == 0) red[t >> 6] = v;
  __syncthreads();
  float var = (red[0] + red[1]) * (1.0f / CZ);

  zn[t] = d * rsqrtf(var + LN_EPS) * w[t] + b[t];
  __syncthreads();

  if (t < NH) {
    float acc = 0.0f;
    #pragma unroll 8
    for (int c = 0; c < CZ; ++c) acc += zn[c] * wz[c * NH + t];
    int i = row >> 8, j = row & 255;
    biasT[(size_t)t * (NR * NR) + (size_t)j * NR + i] = acc * LOG2E;
  }
}

// ---------------------------------------------------------------------------
// Kernel 3: fused q/k/v/g projections (unchanged this round)
// ---------------------------------------------------------------------------
__global__ __launch_bounds__(256) void qkvg_kernel(
    const bf16* __restrict__ mn,
    const float* __restrict__ wq, const float* __restrict__ wk,
    const float* __restrict__ wv, const float* __restrict__ wg,
    const float* __restrict__ bg,
    bf16* __restrict__ qo, bf16* __restrict__ ko,
    bf16* __restrict__ vo, bf16* __restrict__ go) {
  int r0 = blockIdx.x * 8;
  int t = threadIdx.x;
  __shared__ float mrow[8][CM];

  #pragma unroll
  for (int r = 0; r < 8; ++r)
    mrow[r][t] = __bfloat162float(mn[(size_t)(r0 + r) * CM + t]);
  __syncthreads();

  float aq[8] = {}, ak[8] = {}, av[8] = {}, ag[8] = {};
  for (int kk = 0; kk < CM; ++kk) {
    float wqv = wq[kk * 256 + t];
    float wkv = wk[kk * 256 + t];
    float wvv = wv[kk * 256 + t];
    float wgv = wg[kk * 256 + t];
    #pragma unroll
    for (int r = 0; r < 8; ++r) {
      float mv = mrow[r][kk];
      aq[r] = fmaf(mv, wqv, aq[r]);
      ak[r] = fmaf(mv, wkv, ak[r]);
      av[r] = fmaf(mv, wvv, av[r]);
      ag[r] = fmaf(mv, wgv, ag[r]);
    }
  }

  float bgv = bg[t];
  #pragma unroll
  for (int r = 0; r < 8; ++r) {
    size_t idx = (size_t)(r0 + r) * 256 + t;
    qo[idx] = __float2bfloat16(aq[r]);
    ko[idx] = __float2bfloat16(ak[r]);
    vo[idx] = __float2bfloat16(av[r]);
    float s = 1.0f / (1.0f + __expf(-(ag[r] + bgv)));
    go[idx] = __float2bfloat16(s);
  }
}

// ---------------------------------------------------------------------------
// Kernel 4: MFMA attention, one wave per (s, h, 32-q tile). No LDS, no
// barriers. Swapped QK^T (S^T = K·Q^T) so softmax is in-register; P->A-frag
// via v_cvt_pk_bf16_f32 + shfl_xor(32).
//   32x32x16 bf16 MFMA layouts (guide §3, m74/m101):
//     A-frag: lane holds A[lane&31][8*(lane>>5)+j], j=0..7 (contiguous k)
//     B-frag: lane holds B[8*(lane>>5)+j][lane&31]
//     C/D:    lane holds D[crow(r,hi)][lane&31], crow=(r&3)+8*(r>>2)+4*hi
// ---------------------------------------------------------------------------
__global__ __launch_bounds__(256, 2) void attn_mfma_kernel(
    const bf16* __restrict__ qb, const bf16* __restrict__ kb,
    const bf16* __restrict__ vb, const bf16* __restrict__ gb,
    const float* __restrict__ biasT, bf16* __restrict__ gob) {
  int wid = blockIdx.x * 4 + (threadIdx.x >> 6);
  int lane = threadIdx.x & 63;
  int lo = lane & 31;
  int hi = lane >> 5;
  int s = wid >> 6;
  int h = (wid >> 3) & 7;
  int q0 = (wid & 7) * 32;

  const size_t base = (size_t)s * NR * 256 + h * CH;  // element offset of (s, h)

  // ---- Q B-frags: B[c][q] = Q[q0+lo][16*cc + 8*hi + j] ----
  short8 qf[2];
  #pragma unroll
  for (int cc = 0; cc < 2; ++cc) {
    const uint4* p =
        (const uint4*)(qb + base + (size_t)(q0 + lo) * 256 + cc * 16 + hi * 8);
    qf[cc] = __builtin_bit_cast(short8, *p);
  }

  // ---- S^T: acc[t] covers kk in [32t, 32t+32) x q in [q0, q0+32) ----
  f32x16 acc[8];
  #pragma unroll
  for (int t = 0; t < 8; ++t) {
    const uint4* k0 =
        (const uint4*)(kb + base + (size_t)(t * 32 + lo) * 256 + hi * 8);
    const uint4* k1 =
        (const uint4*)(kb + base + (size_t)(t * 32 + lo) * 256 + 16 + hi * 8);
    short8 kf0 = __builtin_bit_cast(short8, *k0);
    short8 kf1 = __builtin_bit_cast(short8, *k1);
    f32x16 z = {};
    acc[t] = __builtin_amdgcn_mfma_f32_32x32x16_bf16(kf0, qf[0], z, 0, 0, 0);
    acc[t] = __builtin_amdgcn_mfma_f32_32x32x16_bf16(kf1, qf[1], acc[t], 0, 0, 0);
  }

  // ---- logits(log2-domain): acc*SCALE2 + biasT[h][kk][q] ----
  const float* bh = biasT + (size_t)h * (NR * NR) + q0 + lo;
  #pragma unroll
  for (int t = 0; t < 8; ++t) {
    #pragma unroll
    for (int r = 0; r < 16; ++r) {
      int kk = t * 32 + (r & 3) + ((r >> 2) << 3) + (hi << 2);
      acc[t][r] = fmaf(acc[t][r], SCALE2, bh[(size_t)kk * NR]);
    }
  }

  // ---- softmax over kk (this lane holds 128 of 256; partner has rest) ----
  float mx = -3.0e38f;
  #pragma unroll
  for (int t = 0; t < 8; ++t)
    #pragma unroll
    for (int r = 0; r < 16; ++r) mx = fmaxf(mx, acc[t][r]);
  mx = fmaxf(mx, __shfl_xor(mx, 32));

  float l = 0.0f;
  #pragma unroll
  for (int t = 0; t < 8; ++t) {
    #pragma unroll
    for (int r = 0; r < 16; ++r) {
      float e = exp2f(acc[t][r] - mx);
      acc[t][r] = e;
      l += e;
    }
  }
  l += __shfl_xor(l, 32);

  // ---- PV: O[q][d] += P-frag(kc) x V-frag(kc), kc = 16-kk chunks ----
  f32x16 o = {};
  const short* vbase = (const short*)vb + base;
  #pragma unroll
  for (int kc = 0; kc < 16; ++kc) {
    int t = kc >> 1;
    int rb = (kc & 1) << 3;
    // pack own 8 P values (q = lo column) as bf16 pairs
    unsigned uL0 = pk_bf16(acc[t][rb + 0], acc[t][rb + 1]);
    unsigned uL1 = pk_bf16(acc[t][rb + 2], acc[t][rb + 3]);
    unsigned uH0 = pk_bf16(acc[t][rb + 4], acc[t][rb + 5]);
    unsigned uH1 = pk_bf16(acc[t][rb + 6], acc[t][rb + 7]);
    // exchange with kk-partner lane (hi flipped)
    unsigned sL0 = __shfl_xor(uL0, 32), sL1 = __shfl_xor(uL1, 32);
    unsigned sH0 = __shfl_xor(uH0, 32), sH1 = __shfl_xor(uH1, 32);
    uint4 pu;
    pu.x = hi ? sH0 : uL0;
    pu.y = hi ? sH1 : uL1;
    pu.z = hi ? uH0 : sL0;
    pu.w = hi ? uH1 : sL1;
    short8 pf = __builtin_bit_cast(short8, pu);
    // V B-frag: B[kk][d] = V[16kc + 8hi + j][lo]
    short8 vf;
    #pragma unroll
    for (int j = 0; j < 8; ++j)
      vf[j] = vbase[(size_t)(kc * 16 + hi * 8 + j) * 256 + lo];
    o = __builtin_amdgcn_mfma_f32_32x32x16_bf16(pf, vf, o, 0, 0, 0);
  }

  // ---- epilogue: gob = g * (o / l); O row q = q0 + crow(r,hi), col d = lo --
  float linv = 1.0f / l;
  #pragma unroll
  for (int r = 0; r < 16; ++r) {
    int crow = (r & 3) + ((r >> 2) << 3) + (hi << 2);
    float li = __shfl(linv, crow);
    size_t idx = base + (size_t)(q0 + crow) * 256 + lo;
    float gg = __bfloat162float(gb[idx]);
    gob[idx] = __float2bfloat16(gg * o[r] * li);
  }
}

// ---------------------------------------------------------------------------
// Kernel 5: out = (g*o) @ w_o + b_o (unchanged this round)
// ---------------------------------------------------------------------------
__global__ __launch_bounds__(256) void out_kernel(
    const bf16* __restrict__ gob, const float* __restrict__ wo,
    const float* __restrict__ bo, float* __restrict__ out) {
  int r0 = blockIdx.x * 8;
  int t = threadIdx.x;
  __shared__ float grow[8][256];

  #pragma unroll
  for (int r = 0; r < 8; ++r)
    grow[r][t] = __bfloat162float(gob[(size_t)(r0 + r) * 256 + t]);
  __syncthreads();

  float acc[8] = {};
  for (int kk = 0; kk < 256; ++kk) {
    float wv = wo[kk * 256 + t];
    #pragma unroll
    for (int r = 0; r < 8; ++r) acc[r] = fmaf(grow[r][kk], wv, acc[r]);
  }

  float bv = bo[t];
  #pragma unroll
  for (int r = 0; r < 8; ++r)
    out[(size_t)(r0 + r) * 256 + t] = acc[r] + bv;
}

// ---------------------------------------------------------------------------
extern "C" void kernel_launch(void* const* d_in, const int* in_sizes, int n_in,
                              void* d_out, int out_size, void* d_ws, size_t ws_size,
                              hipStream_t stream) {
  const float* m      = (const float*)d_in[0];
  const float* z      = (const float*)d_in[1];
  const float* ln_m_w = (const float*)d_in[2];
  const float* ln_m_b = (const float*)d_in[3];
  const float* ln_z_w = (const float*)d_in[4];
  const float* ln_z_b = (const float*)d_in[5];
  const float* w_z    = (const float*)d_in[6];
  const float* w_q    = (const float*)d_in[7];
  const float* w_k    = (const float*)d_in[8];
  const float* w_v    = (const float*)d_in[9];
  const float* w_g    = (const float*)d_in[10];
  const float* b_g    = (const float*)d_in[11];
  const float* w_o    = (const float*)d_in[12];
  const float* b_o    = (const float*)d_in[13];
  float* out = (float*)d_out;

  const size_t SZ = (size_t)NS * NR * 256;

  bf16* mn   = (bf16*)d_ws;
  bf16* qb   = mn + SZ;
  bf16* kb   = qb + SZ;
  bf16* vb   = kb + SZ;
  bf16* gb   = vb + SZ;
  bf16* gob  = gb + SZ;
  float* biasT = (float*)(gob + SZ);  // NH*NR*NR floats = 2 MB

  ln_m_kernel<<<NS * NR, 256, 0, stream>>>(m, ln_m_w, ln_m_b, mn);
  bias_kernel<<<NR * NR, 128, 0, stream>>>(z, ln_z_w, ln_z_b, w_z, biasT);
  qkvg_kernel<<<(NS * NR) / 8, 256, 0, stream>>>(mn, w_q, w_k, w_v, w_g, b_g,
                                                 qb, kb, vb, gb);
  attn_mfma_kernel<<<(NS * NH * 8) / 4, 256, 0, stream>>>(qb, kb, vb, gb,
                                                          biasT, gob);
  out_kernel<<<(NS * NR) / 8, 256, 0, stream>>>(gob, w_o, b_o, out);
}

// Round 3
// 534.319 us; speedup vs baseline: 3.9374x; 1.8477x over previous
//
#include <hip/hip_runtime.h>
#include <hip/hip_bf16.h>

typedef __hip_bfloat16 bf16;
typedef __attribute__((ext_vector_type(8))) short short8;
typedef __attribute__((ext_vector_type(16))) float f32x16;

#define NS 256      // N_SEQ
#define NR 256      // N_RES
#define CM 256      // C_M
#define CZ 128      // C_Z
#define NH 8        // heads
#define CH 32       // head dim
#define LN_EPS 1e-5f
#define LOG2E 1.4426950408889634f
// (1/sqrt(32)) * log2(e): fold into logits so exp == exp2
#define SCALE2 (0.17677669529663687f * 1.4426950408889634f)

__device__ __forceinline__ unsigned pk_bf16(float lo, float hi) {
  unsigned r;
  asm volatile("v_cvt_pk_bf16_f32 %0, %1, %2" : "=v"(r) : "v"(lo), "v"(hi));
  return r;
}

__device__ __forceinline__ short8 load8(const bf16* p) {
  return __builtin_bit_cast(short8, *(const uint4*)p);
}

// ---------------------------------------------------------------------------
// Kernel 0: pack 5 weight matrices (each [256][256] f32) into bf16 B-frag
// layout: wp[mat][kc][hi][n][j] = w[kc*16 + hi*8 + j][n]
// grid (32, 5), 256 threads
// ---------------------------------------------------------------------------
__global__ __launch_bounds__(256) void pack_w_kernel(
    const float* __restrict__ wq, const float* __restrict__ wk,
    const float* __restrict__ wv, const float* __restrict__ wg,
    const float* __restrict__ wo, bf16* __restrict__ dst) {
  int mat = blockIdx.y;
  const float* src = mat == 0 ? wq : mat == 1 ? wk : mat == 2 ? wv
                   : mat == 3 ? wg : wo;
  int t = blockIdx.x * 256 + threadIdx.x;  // 0..8191
  int n = t & 255;
  int hi = (t >> 8) & 1;
  int kc = t >> 9;
  int kbase = kc * 16 + hi * 8;
  bf16 tmp[8];
  #pragma unroll
  for (int j = 0; j < 8; ++j)
    tmp[j] = __float2bfloat16(src[(size_t)(kbase + j) * 256 + n]);
  *(uint4*)(dst + (size_t)mat * 65536 +
            ((size_t)(kc * 2 + hi) * 256 + n) * 8) = *(const uint4*)tmp;
}

// ---------------------------------------------------------------------------
// Kernel 1: LayerNorm over m's channel dim, output bf16
// ---------------------------------------------------------------------------
__global__ __launch_bounds__(256) void ln_m_kernel(
    const float* __restrict__ m, const float* __restrict__ w,
    const float* __restrict__ b, bf16* __restrict__ mn) {
  int row = blockIdx.x;
  int t = threadIdx.x;
  __shared__ float red[4];

  float x = m[(size_t)row * CM + t];

  float v = x;
  #pragma unroll
  for (int off = 32; off; off >>= 1) v += __shfl_xor(v, off);
  if ((t & 63) == 0) red[t >> 6] = v;
  __syncthreads();
  float mu = (red[0] + red[1] + red[2] + red[3]) * (1.0f / CM);
  float d = x - mu;
  __syncthreads();

  v = d * d;
  #pragma unroll
  for (int off = 32; off; off >>= 1) v += __shfl_xor(v, off);
  if ((t & 63) == 0) red[t >> 6] = v;
  __syncthreads();
  float var = (red[0] + red[1] + red[2] + red[3]) * (1.0f / CM);

  float y = d * rsqrtf(var + LN_EPS) * w[t] + b[t];
  mn[(size_t)row * CM + t] = __float2bfloat16(y);
}

// ---------------------------------------------------------------------------
// Kernel 2: biasT[h][k][q] = (LN(z[q,k,:]) @ w_z)[h] * log2(e)   (transposed!)
// ---------------------------------------------------------------------------
__global__ __launch_bounds__(128) void bias_kernel(
    const float* __restrict__ z, const float* __restrict__ w,
    const float* __restrict__ b, const float* __restrict__ wz,
    float* __restrict__ biasT) {
  int row = blockIdx.x;   // i*NR + j  (i = q, j = k)
  int t = threadIdx.x;    // 0..127
  __shared__ float red[2];
  __shared__ float zn[CZ];

  float x = z[(size_t)row * CZ + t];

  float v = x;
  #pragma unroll
  for (int off = 32; off; off >>= 1) v += __shfl_xor(v, off);
  if ((t & 63) == 0) red[t >> 6] = v;
  __syncthreads();
  float mu = (red[0] + red[1]) * (1.0f / CZ);
  float d = x - mu;
  __syncthreads();

  v = d * d;
  #pragma unroll
  for (int off = 32; off; off >>= 1) v += __shfl_xor(v, off);
  if ((t & 63) == 0) red[t >> 6] = v;
  __syncthreads();
  float var = (red[0] + red[1]) * (1.0f / CZ);

  zn[t] = d * rsqrtf(var + LN_EPS) * w[t] + b[t];
  __syncthreads();

  if (t < NH) {
    float acc = 0.0f;
    #pragma unroll 8
    for (int c = 0; c < CZ; ++c) acc += zn[c] * wz[c * NH + t];
    int i = row >> 8, j = row & 255;
    biasT[(size_t)t * (NR * NR) + (size_t)j * NR + i] = acc * LOG2E;
  }
}

// ---------------------------------------------------------------------------
// Kernel 3: fused q/k/v/g projections via MFMA. One wave per 32 rows of mn;
// A (32x256) held in registers; B streamed from L2 in frag-native layout.
// N = 1024 fused (q|k|v|g), 32 N-tiles x 16 MFMAs.
// ---------------------------------------------------------------------------
__global__ __launch_bounds__(256, 2) void qkvg_mfma_kernel(
    const bf16* __restrict__ mn, const bf16* __restrict__ wp,
    const float* __restrict__ bg,
    bf16* __restrict__ qo, bf16* __restrict__ ko,
    bf16* __restrict__ vo, bf16* __restrict__ go) {
  int wid = blockIdx.x * 4 + (threadIdx.x >> 6);
  int lane = threadIdx.x & 63;
  int lo = lane & 31, hi = lane >> 5;
  size_t m0 = (size_t)wid * 32;

  short8 af[16];
  const bf16* arow = mn + (m0 + lo) * 256 + hi * 8;
  #pragma unroll
  for (int kc = 0; kc < 16; ++kc) af[kc] = load8(arow + kc * 16);

  #pragma unroll 1
  for (int nt = 0; nt < 32; ++nt) {
    int mat = nt >> 3;
    int n0 = (nt & 7) * 32;
    const bf16* wpm =
        wp + (size_t)mat * 65536 + ((size_t)hi * 256 + n0 + lo) * 8;
    f32x16 acc = {};
    #pragma unroll
    for (int kc = 0; kc < 16; ++kc) {
      short8 bfr = load8(wpm + (size_t)kc * 4096);
      acc = __builtin_amdgcn_mfma_f32_32x32x16_bf16(af[kc], bfr, acc, 0, 0, 0);
    }
    bf16* o = mat == 0 ? qo : mat == 1 ? ko : mat == 2 ? vo : go;
    if (mat < 3) {
      #pragma unroll
      for (int r = 0; r < 16; ++r) {
        int crow = (r & 3) + ((r >> 2) << 3) + (hi << 2);
        o[(m0 + crow) * 256 + n0 + lo] = __float2bfloat16(acc[r]);
      }
    } else {
      float bgv = bg[n0 + lo];
      #pragma unroll
      for (int r = 0; r < 16; ++r) {
        int crow = (r & 3) + ((r >> 2) << 3) + (hi << 2);
        float sv = 1.0f / (1.0f + __expf(-(acc[r] + bgv)));
        o[(m0 + crow) * 256 + n0 + lo] = __float2bfloat16(sv);
      }
    }
  }
}

// ---------------------------------------------------------------------------
// Kernel 4: MFMA attention, one wave per (s, h, 32-q tile). No LDS, no
// barriers. Swapped QK^T (S^T = K·Q^T) so softmax is in-register; P->A-frag
// via v_cvt_pk_bf16_f32 + shfl_xor(32).
// ---------------------------------------------------------------------------
__global__ __launch_bounds__(256, 2) void attn_mfma_kernel(
    const bf16* __restrict__ qb, const bf16* __restrict__ kb,
    const bf16* __restrict__ vb, const bf16* __restrict__ gb,
    const float* __restrict__ biasT, bf16* __restrict__ gob) {
  int wid = blockIdx.x * 4 + (threadIdx.x >> 6);
  int lane = threadIdx.x & 63;
  int lo = lane & 31;
  int hi = lane >> 5;
  int s = wid >> 6;
  int h = (wid >> 3) & 7;
  int q0 = (wid & 7) * 32;

  const size_t base = (size_t)s * NR * 256 + h * CH;

  short8 qf[2];
  #pragma unroll
  for (int cc = 0; cc < 2; ++cc)
    qf[cc] = load8(qb + base + (size_t)(q0 + lo) * 256 + cc * 16 + hi * 8);

  f32x16 acc[8];
  #pragma unroll
  for (int t = 0; t < 8; ++t) {
    short8 kf0 = load8(kb + base + (size_t)(t * 32 + lo) * 256 + hi * 8);
    short8 kf1 = load8(kb + base + (size_t)(t * 32 + lo) * 256 + 16 + hi * 8);
    f32x16 z = {};
    acc[t] = __builtin_amdgcn_mfma_f32_32x32x16_bf16(kf0, qf[0], z, 0, 0, 0);
    acc[t] = __builtin_amdgcn_mfma_f32_32x32x16_bf16(kf1, qf[1], acc[t], 0, 0, 0);
  }

  const float* bh = biasT + (size_t)h * (NR * NR) + q0 + lo;
  #pragma unroll
  for (int t = 0; t < 8; ++t) {
    #pragma unroll
    for (int r = 0; r < 16; ++r) {
      int kk = t * 32 + (r & 3) + ((r >> 2) << 3) + (hi << 2);
      acc[t][r] = fmaf(acc[t][r], SCALE2, bh[(size_t)kk * NR]);
    }
  }

  float mx = -3.0e38f;
  #pragma unroll
  for (int t = 0; t < 8; ++t)
    #pragma unroll
    for (int r = 0; r < 16; ++r) mx = fmaxf(mx, acc[t][r]);
  mx = fmaxf(mx, __shfl_xor(mx, 32));

  float l = 0.0f;
  #pragma unroll
  for (int t = 0; t < 8; ++t) {
    #pragma unroll
    for (int r = 0; r < 16; ++r) {
      float e = exp2f(acc[t][r] - mx);
      acc[t][r] = e;
      l += e;
    }
  }
  l += __shfl_xor(l, 32);

  f32x16 o = {};
  const short* vbase = (const short*)vb + base;
  #pragma unroll
  for (int kc = 0; kc < 16; ++kc) {
    int t = kc >> 1;
    int rb = (kc & 1) << 3;
    unsigned uL0 = pk_bf16(acc[t][rb + 0], acc[t][rb + 1]);
    unsigned uL1 = pk_bf16(acc[t][rb + 2], acc[t][rb + 3]);
    unsigned uH0 = pk_bf16(acc[t][rb + 4], acc[t][rb + 5]);
    unsigned uH1 = pk_bf16(acc[t][rb + 6], acc[t][rb + 7]);
    unsigned sL0 = __shfl_xor(uL0, 32), sL1 = __shfl_xor(uL1, 32);
    unsigned sH0 = __shfl_xor(uH0, 32), sH1 = __shfl_xor(uH1, 32);
    uint4 pu;
    pu.x = hi ? sH0 : uL0;
    pu.y = hi ? sH1 : uL1;
    pu.z = hi ? uH0 : sL0;
    pu.w = hi ? uH1 : sL1;
    short8 pf = __builtin_bit_cast(short8, pu);
    short8 vf;
    #pragma unroll
    for (int j = 0; j < 8; ++j)
      vf[j] = vbase[(size_t)(kc * 16 + hi * 8 + j) * 256 + lo];
    o = __builtin_amdgcn_mfma_f32_32x32x16_bf16(pf, vf, o, 0, 0, 0);
  }

  float linv = 1.0f / l;
  #pragma unroll
  for (int r = 0; r < 16; ++r) {
    int crow = (r & 3) + ((r >> 2) << 3) + (hi << 2);
    float li = __shfl(linv, crow);
    size_t idx = base + (size_t)(q0 + crow) * 256 + lo;
    float gg = __bfloat162float(gb[idx]);
    gob[idx] = __float2bfloat16(gg * o[r] * li);
  }
}

// ---------------------------------------------------------------------------
// Kernel 5: out = (g*o) @ w_o + b_o via MFMA, f32 output.
// ---------------------------------------------------------------------------
__global__ __launch_bounds__(256, 2) void out_mfma_kernel(
    const bf16* __restrict__ gob, const bf16* __restrict__ wop,
    const float* __restrict__ bo, float* __restrict__ out) {
  int wid = blockIdx.x * 4 + (threadIdx.x >> 6);
  int lane = threadIdx.x & 63;
  int lo = lane & 31, hi = lane >> 5;
  size_t m0 = (size_t)wid * 32;

  short8 af[16];
  const bf16* arow = gob + (m0 + lo) * 256 + hi * 8;
  #pragma unroll
  for (int kc = 0; kc < 16; ++kc) af[kc] = load8(arow + kc * 16);

  #pragma unroll 1
  for (int nt = 0; nt < 8; ++nt) {
    int n0 = nt * 32;
    const bf16* wpm = wop + ((size_t)hi * 256 + n0 + lo) * 8;
    f32x16 acc = {};
    #pragma unroll
    for (int kc = 0; kc < 16; ++kc) {
      short8 bfr = load8(wpm + (size_t)kc * 4096);
      acc = __builtin_amdgcn_mfma_f32_32x32x16_bf16(af[kc], bfr, acc, 0, 0, 0);
    }
    float bv = bo[n0 + lo];
    #pragma unroll
    for (int r = 0; r < 16; ++r) {
      int crow = (r & 3) + ((r >> 2) << 3) + (hi << 2);
      out[(m0 + crow) * 256 + n0 + lo] = acc[r] + bv;
    }
  }
}

// ---------------------------------------------------------------------------
extern "C" void kernel_launch(void* const* d_in, const int* in_sizes, int n_in,
                              void* d_out, int out_size, void* d_ws, size_t ws_size,
                              hipStream_t stream) {
  const float* m      = (const float*)d_in[0];
  const float* z      = (const float*)d_in[1];
  const float* ln_m_w = (const float*)d_in[2];
  const float* ln_m_b = (const float*)d_in[3];
  const float* ln_z_w = (const float*)d_in[4];
  const float* ln_z_b = (const float*)d_in[5];
  const float* w_z    = (const float*)d_in[6];
  const float* w_q    = (const float*)d_in[7];
  const float* w_k    = (const float*)d_in[8];
  const float* w_v    = (const float*)d_in[9];
  const float* w_g    = (const float*)d_in[10];
  const float* b_g    = (const float*)d_in[11];
  const float* w_o    = (const float*)d_in[12];
  const float* b_o    = (const float*)d_in[13];
  float* out = (float*)d_out;

  const size_t SZ = (size_t)NS * NR * 256;

  bf16* mn   = (bf16*)d_ws;
  bf16* qb   = mn + SZ;
  bf16* kb   = qb + SZ;
  bf16* vb   = kb + SZ;
  bf16* gb   = vb + SZ;
  bf16* gob  = gb + SZ;
  float* biasT = (float*)(gob + SZ);            // 2 MB
  bf16* wp   = (bf16*)(biasT + NH * NR * NR);   // 5*65536 bf16 = 640 KB
  bf16* wop  = wp + 4 * 65536;

  pack_w_kernel<<<dim3(32, 5), 256, 0, stream>>>(w_q, w_k, w_v, w_g, w_o, wp);
  ln_m_kernel<<<NS * NR, 256, 0, stream>>>(m, ln_m_w, ln_m_b, mn);
  bias_kernel<<<NR * NR, 128, 0, stream>>>(z, ln_z_w, ln_z_b, w_z, biasT);
  qkvg_mfma_kernel<<<(NS * NR) / 32 / 4, 256, 0, stream>>>(
      mn, wp, b_g, qb, kb, vb, gb);
  attn_mfma_kernel<<<(NS * NH * 8) / 4, 256, 0, stream>>>(qb, kb, vb, gb,
                                                          biasT, gob);
  out_mfma_kernel<<<(NS * NR) / 32 / 4, 256, 0, stream>>>(gob, wop, b_o, out);
}

// Round 4
// 403.401 us; speedup vs baseline: 5.2153x; 1.3245x over previous
//
#include <hip/hip_runtime.h>
#include <hip/hip_bf16.h>

typedef __hip_bfloat16 bf16;
typedef __attribute__((ext_vector_type(8))) short short8;
typedef __attribute__((ext_vector_type(16))) float f32x16;

#define NS 256      // N_SEQ
#define NR 256      // N_RES
#define CM 256      // C_M
#define CZ 128      // C_Z
#define NH 8        // heads
#define CH 32       // head dim
#define LN_EPS 1e-5f
#define LOG2E 1.4426950408889634f
// (1/sqrt(32)) * log2(e): fold into logits so exp == exp2
#define SCALE2 (0.17677669529663687f * 1.4426950408889634f)

__device__ __forceinline__ unsigned pk_bf16(float lo, float hi) {
  unsigned r;
  asm volatile("v_cvt_pk_bf16_f32 %0, %1, %2" : "=v"(r) : "v"(lo), "v"(hi));
  return r;
}

__device__ __forceinline__ short8 load8(const bf16* p) {
  return __builtin_bit_cast(short8, *(const uint4*)p);
}

// ---------------------------------------------------------------------------
// Kernel 0: pack 5 weight matrices (each [256][256] f32) into bf16 B-frag
// layout: wp[mat][kc][hi][n][j] = w[kc*16 + hi*8 + j][n]
// ---------------------------------------------------------------------------
__global__ __launch_bounds__(256) void pack_w_kernel(
    const float* __restrict__ wq, const float* __restrict__ wk,
    const float* __restrict__ wv, const float* __restrict__ wg,
    const float* __restrict__ wo, bf16* __restrict__ dst) {
  int mat = blockIdx.y;
  const float* src = mat == 0 ? wq : mat == 1 ? wk : mat == 2 ? wv
                   : mat == 3 ? wg : wo;
  int t = blockIdx.x * 256 + threadIdx.x;  // 0..8191
  int n = t & 255;
  int hi = (t >> 8) & 1;
  int kc = t >> 9;
  int kbase = kc * 16 + hi * 8;
  bf16 tmp[8];
  #pragma unroll
  for (int j = 0; j < 8; ++j)
    tmp[j] = __float2bfloat16(src[(size_t)(kbase + j) * 256 + n]);
  *(uint4*)(dst + (size_t)mat * 65536 +
            ((size_t)(kc * 2 + hi) * 256 + n) * 8) = *(const uint4*)tmp;
}

// ---------------------------------------------------------------------------
// Kernel 1: LayerNorm over m, one wave per row, float4 loads, bf16x4 stores
// grid = NS*NR/4 blocks, 256 threads (4 waves)
// ---------------------------------------------------------------------------
__global__ __launch_bounds__(256) void ln_m_kernel(
    const float* __restrict__ m, const float* __restrict__ w,
    const float* __restrict__ b, bf16* __restrict__ mn) {
  int row = blockIdx.x * 4 + (threadIdx.x >> 6);
  int lane = threadIdx.x & 63;

  float4 x = ((const float4*)(m + (size_t)row * CM))[lane];
  float sum = x.x + x.y + x.z + x.w;
  #pragma unroll
  for (int off = 32; off; off >>= 1) sum += __shfl_xor(sum, off);
  float mu = sum * (1.0f / CM);

  float dx = x.x - mu, dy = x.y - mu, dz = x.z - mu, dw = x.w - mu;
  float ss = dx * dx + dy * dy + dz * dz + dw * dw;
  #pragma unroll
  for (int off = 32; off; off >>= 1) ss += __shfl_xor(ss, off);
  float rs = rsqrtf(ss * (1.0f / CM) + LN_EPS);

  float4 wv = ((const float4*)w)[lane];
  float4 bv = ((const float4*)b)[lane];
  unsigned p0 = pk_bf16(dx * rs * wv.x + bv.x, dy * rs * wv.y + bv.y);
  unsigned p1 = pk_bf16(dz * rs * wv.z + bv.z, dw * rs * wv.w + bv.w);
  uint2 u;
  u.x = p0;
  u.y = p1;
  *(uint2*)(mn + (size_t)row * CM + lane * 4) = u;
}

// ---------------------------------------------------------------------------
// Kernel 2: biasT[h][k][q] = (LN(z[q,k,:]) @ w_z)[h] * log2(e)   (transposed)
// 128 threads; matmul tail parallelized across all threads.
// ---------------------------------------------------------------------------
__global__ __launch_bounds__(128) void bias_kernel(
    const float* __restrict__ z, const float* __restrict__ w,
    const float* __restrict__ b, const float* __restrict__ wz,
    float* __restrict__ biasT) {
  int row = blockIdx.x;   // i*NR + j  (i = q, j = k)
  int t = threadIdx.x;    // 0..127
  __shared__ float red[2];
  __shared__ float zn[CZ];
  __shared__ float part[16][9];

  float x = z[(size_t)row * CZ + t];

  float v = x;
  #pragma unroll
  for (int off = 32; off; off >>= 1) v += __shfl_xor(v, off);
  if ((t & 63) == 0) red[t >> 6] = v;
  __syncthreads();
  float mu = (red[0] + red[1]) * (1.0f / CZ);
  float d = x - mu;
  __syncthreads();

  v = d * d;
  #pragma unroll
  for (int off = 32; off; off >>= 1) v += __shfl_xor(v, off);
  if ((t & 63) == 0) red[t >> 6] = v;
  __syncthreads();
  float var = (red[0] + red[1]) * (1.0f / CZ);

  zn[t] = d * rsqrtf(var + LN_EPS) * w[t] + b[t];
  __syncthreads();

  int h = t & 7, grp = t >> 3;
  float acc = 0.0f;
  #pragma unroll
  for (int cc = 0; cc < 8; ++cc) {
    int c = grp * 8 + cc;
    acc += zn[c] * wz[c * NH + h];
  }
  part[grp][h] = acc;
  __syncthreads();

  if (t < NH) {
    float s = 0.0f;
    #pragma unroll
    for (int g = 0; g < 16; ++g) s += part[g][t];
    int i = row >> 8, j = row & 255;
    biasT[(size_t)t * (NR * NR) + (size_t)j * NR + i] = s * LOG2E;
  }
}

// ---------------------------------------------------------------------------
// Kernel 3: fused q/k/v/g projections via MFMA. One wave per (32-row tile,
// matrix). Block's 4 waves share one matrix (L1 reuse of B-frags).
// v is computed with swapped operands -> stored transposed as vT[s][h][c][k].
// ---------------------------------------------------------------------------
__global__ __launch_bounds__(256, 4) void qkvg_mfma_kernel(
    const bf16* __restrict__ mn, const bf16* __restrict__ wp,
    const float* __restrict__ bg,
    bf16* __restrict__ qo, bf16* __restrict__ ko,
    bf16* __restrict__ vT, bf16* __restrict__ go) {
  int wid = blockIdx.x * 4 + (threadIdx.x >> 6);  // 0..8191
  int mat = wid >> 11;                            // 0..3  (q,k,v,g)
  int mtile = wid & 2047;
  int lane = threadIdx.x & 63;
  int lo = lane & 31, hi = lane >> 5;
  size_t m0 = (size_t)mtile * 32;

  short8 af[16];
  const bf16* arow = mn + (m0 + lo) * 256 + hi * 8;
  #pragma unroll
  for (int kc = 0; kc < 16; ++kc) af[kc] = load8(arow + kc * 16);

  const bf16* wmat = wp + (size_t)mat * 65536;

  #pragma unroll 1
  for (int nt = 0; nt < 8; ++nt) {
    int n0 = nt * 32;
    const bf16* wpm = wmat + ((size_t)hi * 256 + n0 + lo) * 8;
    f32x16 acc = {};
    if (mat == 2) {
      // D' = (mn W_v)^T tile: lane lo = row m, crow = n within tile
      #pragma unroll
      for (int kc = 0; kc < 16; ++kc) {
        short8 bfr = load8(wpm + (size_t)kc * 4096);
        acc = __builtin_amdgcn_mfma_f32_32x32x16_bf16(bfr, af[kc], acc, 0, 0, 0);
      }
      int s = (int)(m0 >> 8);
      int k0 = (int)(m0 & 255);
      #pragma unroll
      for (int r = 0; r < 16; ++r) {
        int crow = (r & 3) + ((r >> 2) << 3) + (hi << 2);
        int n = n0 + crow;  // h = n>>5, c = n&31
        size_t idx = (((size_t)s * NH + (n >> 5)) * CH + (n & 31)) * 256 +
                     k0 + lo;
        vT[idx] = __float2bfloat16(acc[r]);
      }
    } else {
      #pragma unroll
      for (int kc = 0; kc < 16; ++kc) {
        short8 bfr = load8(wpm + (size_t)kc * 4096);
        acc = __builtin_amdgcn_mfma_f32_32x32x16_bf16(af[kc], bfr, acc, 0, 0, 0);
      }
      if (mat == 3) {
        float bgv = bg[n0 + lo];
        #pragma unroll
        for (int r = 0; r < 16; ++r) {
          int crow = (r & 3) + ((r >> 2) << 3) + (hi << 2);
          float sv = 1.0f / (1.0f + __expf(-(acc[r] + bgv)));
          go[(m0 + crow) * 256 + n0 + lo] = __float2bfloat16(sv);
        }
      } else {
        bf16* o = mat == 0 ? qo : ko;
        #pragma unroll
        for (int r = 0; r < 16; ++r) {
          int crow = (r & 3) + ((r >> 2) << 3) + (hi << 2);
          o[(m0 + crow) * 256 + n0 + lo] = __float2bfloat16(acc[r]);
        }
      }
    }
  }
}

// ---------------------------------------------------------------------------
// Kernel 4: MFMA attention, one wave per (s, h, 32-q tile). No LDS, no
// barriers. Swapped QK^T; V read from vT as direct B-frag load8.
// ---------------------------------------------------------------------------
__global__ __launch_bounds__(256, 2) void attn_mfma_kernel(
    const bf16* __restrict__ qb, const bf16* __restrict__ kb,
    const bf16* __restrict__ vT, const bf16* __restrict__ gb,
    const float* __restrict__ biasT, bf16* __restrict__ gob) {
  int wid = blockIdx.x * 4 + (threadIdx.x >> 6);
  int lane = threadIdx.x & 63;
  int lo = lane & 31;
  int hi = lane >> 5;
  int s = wid >> 6;
  int h = (wid >> 3) & 7;
  int q0 = (wid & 7) * 32;

  const size_t base = (size_t)s * NR * 256 + h * CH;

  short8 qf[2];
  #pragma unroll
  for (int cc = 0; cc < 2; ++cc)
    qf[cc] = load8(qb + base + (size_t)(q0 + lo) * 256 + cc * 16 + hi * 8);

  f32x16 acc[8];
  #pragma unroll
  for (int t = 0; t < 8; ++t) {
    short8 kf0 = load8(kb + base + (size_t)(t * 32 + lo) * 256 + hi * 8);
    short8 kf1 = load8(kb + base + (size_t)(t * 32 + lo) * 256 + 16 + hi * 8);
    f32x16 z = {};
    acc[t] = __builtin_amdgcn_mfma_f32_32x32x16_bf16(kf0, qf[0], z, 0, 0, 0);
    acc[t] = __builtin_amdgcn_mfma_f32_32x32x16_bf16(kf1, qf[1], acc[t], 0, 0, 0);
  }

  const float* bh = biasT + (size_t)h * (NR * NR) + q0 + lo;
  #pragma unroll
  for (int t = 0; t < 8; ++t) {
    #pragma unroll
    for (int r = 0; r < 16; ++r) {
      int kk = t * 32 + (r & 3) + ((r >> 2) << 3) + (hi << 2);
      acc[t][r] = fmaf(acc[t][r], SCALE2, bh[(size_t)kk * NR]);
    }
  }

  float mx = -3.0e38f;
  #pragma unroll
  for (int t = 0; t < 8; ++t)
    #pragma unroll
    for (int r = 0; r < 16; ++r) mx = fmaxf(mx, acc[t][r]);
  mx = fmaxf(mx, __shfl_xor(mx, 32));

  float l = 0.0f;
  #pragma unroll
  for (int t = 0; t < 8; ++t) {
    #pragma unroll
    for (int r = 0; r < 16; ++r) {
      float e = exp2f(acc[t][r] - mx);
      acc[t][r] = e;
      l += e;
    }
  }
  l += __shfl_xor(l, 32);

  f32x16 o = {};
  const bf16* vt = vT + ((size_t)(s * NH + h) * CH + lo) * 256;
  #pragma unroll
  for (int kc = 0; kc < 16; ++kc) {
    int t = kc >> 1;
    int rb = (kc & 1) << 3;
    unsigned uL0 = pk_bf16(acc[t][rb + 0], acc[t][rb + 1]);
    unsigned uL1 = pk_bf16(acc[t][rb + 2], acc[t][rb + 3]);
    unsigned uH0 = pk_bf16(acc[t][rb + 4], acc[t][rb + 5]);
    unsigned uH1 = pk_bf16(acc[t][rb + 6], acc[t][rb + 7]);
    unsigned sL0 = __shfl_xor(uL0, 32), sL1 = __shfl_xor(uL1, 32);
    unsigned sH0 = __shfl_xor(uH0, 32), sH1 = __shfl_xor(uH1, 32);
    uint4 pu;
    pu.x = hi ? sH0 : uL0;
    pu.y = hi ? sH1 : uL1;
    pu.z = hi ? uH0 : sL0;
    pu.w = hi ? uH1 : sL1;
    short8 pf = __builtin_bit_cast(short8, pu);
    short8 vf = load8(vt + kc * 16 + hi * 8);
    o = __builtin_amdgcn_mfma_f32_32x32x16_bf16(pf, vf, o, 0, 0, 0);
  }

  float linv = 1.0f / l;
  #pragma unroll
  for (int r = 0; r < 16; ++r) {
    int crow = (r & 3) + ((r >> 2) << 3) + (hi << 2);
    float li = __shfl(linv, crow);
    size_t idx = base + (size_t)(q0 + crow) * 256 + lo;
    float gg = __bfloat162float(gb[idx]);
    gob[idx] = __float2bfloat16(gg * o[r] * li);
  }
}

// ---------------------------------------------------------------------------
// Kernel 5: out = (g*o) @ w_o + b_o via MFMA. One wave per (32-row tile,
// 128-col half); block's 4 waves share the half (L1 reuse).
// ---------------------------------------------------------------------------
__global__ __launch_bounds__(256, 4) void out_mfma_kernel(
    const bf16* __restrict__ gob, const bf16* __restrict__ wop,
    const float* __restrict__ bo, float* __restrict__ out) {
  int wid = blockIdx.x * 4 + (threadIdx.x >> 6);  // 0..4095
  int half = wid >> 11;
  int mtile = wid & 2047;
  int lane = threadIdx.x & 63;
  int lo = lane & 31, hi = lane >> 5;
  size_t m0 = (size_t)mtile * 32;

  short8 af[16];
  const bf16* arow = gob + (m0 + lo) * 256 + hi * 8;
  #pragma unroll
  for (int kc = 0; kc < 16; ++kc) af[kc] = load8(arow + kc * 16);

  #pragma unroll 1
  for (int nt = 0; nt < 4; ++nt) {
    int n0 = (half * 4 + nt) * 32;
    const bf16* wpm = wop + ((size_t)hi * 256 + n0 + lo) * 8;
    f32x16 acc = {};
    #pragma unroll
    for (int kc = 0; kc < 16; ++kc) {
      short8 bfr = load8(wpm + (size_t)kc * 4096);
      acc = __builtin_amdgcn_mfma_f32_32x32x16_bf16(af[kc], bfr, acc, 0, 0, 0);
    }
    float bv = bo[n0 + lo];
    #pragma unroll
    for (int r = 0; r < 16; ++r) {
      int crow = (r & 3) + ((r >> 2) << 3) + (hi << 2);
      out[(m0 + crow) * 256 + n0 + lo] = acc[r] + bv;
    }
  }
}

// ---------------------------------------------------------------------------
extern "C" void kernel_launch(void* const* d_in, const int* in_sizes, int n_in,
                              void* d_out, int out_size, void* d_ws, size_t ws_size,
                              hipStream_t stream) {
  const float* m      = (const float*)d_in[0];
  const float* z      = (const float*)d_in[1];
  const float* ln_m_w = (const float*)d_in[2];
  const float* ln_m_b = (const float*)d_in[3];
  const float* ln_z_w = (const float*)d_in[4];
  const float* ln_z_b = (const float*)d_in[5];
  const float* w_z    = (const float*)d_in[6];
  const float* w_q    = (const float*)d_in[7];
  const float* w_k    = (const float*)d_in[8];
  const float* w_v    = (const float*)d_in[9];
  const float* w_g    = (const float*)d_in[10];
  const float* b_g    = (const float*)d_in[11];
  const float* w_o    = (const float*)d_in[12];
  const float* b_o    = (const float*)d_in[13];
  float* out = (float*)d_out;

  const size_t SZ = (size_t)NS * NR * 256;

  bf16* mn   = (bf16*)d_ws;
  bf16* qb   = mn + SZ;
  bf16* kb   = qb + SZ;
  bf16* vT   = kb + SZ;
  bf16* gb   = vT + SZ;
  bf16* gob  = gb + SZ;
  float* biasT = (float*)(gob + SZ);            // 2 MB
  bf16* wp   = (bf16*)(biasT + NH * NR * NR);   // 5*65536 bf16 = 640 KB
  bf16* wop  = wp + 4 * 65536;

  pack_w_kernel<<<dim3(32, 5), 256, 0, stream>>>(w_q, w_k, w_v, w_g, w_o, wp);
  ln_m_kernel<<<(NS * NR) / 4, 256, 0, stream>>>(m, ln_m_w, ln_m_b, mn);
  bias_kernel<<<NR * NR, 128, 0, stream>>>(z, ln_z_w, ln_z_b, w_z, biasT);
  qkvg_mfma_kernel<<<(NS * NR) / 32, 256, 0, stream>>>(mn, wp, b_g,
                                                       qb, kb, vT, gb);
  attn_mfma_kernel<<<(NS * NH * 8) / 4, 256, 0, stream>>>(qb, kb, vT, gb,
                                                          biasT, gob);
  out_mfma_kernel<<<(NS * NR) / 32 / 2, 256, 0, stream>>>(gob, wop, b_o, out);
}

// Round 5
// 314.659 us; speedup vs baseline: 6.6861x; 1.2820x over previous
//
#include <hip/hip_runtime.h>
#include <hip/hip_bf16.h>

typedef __hip_bfloat16 bf16;
typedef __attribute__((ext_vector_type(8))) short short8;
typedef __attribute__((ext_vector_type(16))) float f32x16;

#define NS 256      // N_SEQ
#define NR 256      // N_RES
#define CM 256      // C_M
#define CZ 128      // C_Z
#define NH 8        // heads
#define CH 32       // head dim
#define LN_EPS 1e-5f
#define LOG2E 1.4426950408889634f
// (1/sqrt(32)) * log2(e): fold into logits so exp == exp2
#define SCALE2 (0.17677669529663687f * 1.4426950408889634f)

__device__ __forceinline__ unsigned pk_bf16(float lo, float hi) {
  unsigned r;
  asm volatile("v_cvt_pk_bf16_f32 %0, %1, %2" : "=v"(r) : "v"(lo), "v"(hi));
  return r;
}

__device__ __forceinline__ short8 load8(const bf16* p) {
  return __builtin_bit_cast(short8, *(const uint4*)p);
}

// ---------------------------------------------------------------------------
// Kernel 0: pack 5 weight matrices (each [256][256] f32) into bf16 B-frag
// layout: wp[mat][kc][hi][n][j] = w[kc*16 + hi*8 + j][n]
// ---------------------------------------------------------------------------
__global__ __launch_bounds__(256) void pack_w_kernel(
    const float* __restrict__ wq, const float* __restrict__ wk,
    const float* __restrict__ wv, const float* __restrict__ wg,
    const float* __restrict__ wo, bf16* __restrict__ dst) {
  int mat = blockIdx.y;
  const float* src = mat == 0 ? wq : mat == 1 ? wk : mat == 2 ? wv
                   : mat == 3 ? wg : wo;
  int t = blockIdx.x * 256 + threadIdx.x;  // 0..8191
  int n = t & 255;
  int hi = (t >> 8) & 1;
  int kc = t >> 9;
  int kbase = kc * 16 + hi * 8;
  bf16 tmp[8];
  #pragma unroll
  for (int j = 0; j < 8; ++j)
    tmp[j] = __float2bfloat16(src[(size_t)(kbase + j) * 256 + n]);
  *(uint4*)(dst + (size_t)mat * 65536 +
            ((size_t)(kc * 2 + hi) * 256 + n) * 8) = *(const uint4*)tmp;
}

// ---------------------------------------------------------------------------
// Kernel 1: LayerNorm over m, one wave per row, float4 loads, bf16x4 stores
// ---------------------------------------------------------------------------
__global__ __launch_bounds__(256) void ln_m_kernel(
    const float* __restrict__ m, const float* __restrict__ w,
    const float* __restrict__ b, bf16* __restrict__ mn) {
  int row = blockIdx.x * 4 + (threadIdx.x >> 6);
  int lane = threadIdx.x & 63;

  float4 x = ((const float4*)(m + (size_t)row * CM))[lane];
  float sum = x.x + x.y + x.z + x.w;
  #pragma unroll
  for (int off = 32; off; off >>= 1) sum += __shfl_xor(sum, off);
  float mu = sum * (1.0f / CM);

  float dx = x.x - mu, dy = x.y - mu, dz = x.z - mu, dw = x.w - mu;
  float ss = dx * dx + dy * dy + dz * dz + dw * dw;
  #pragma unroll
  for (int off = 32; off; off >>= 1) ss += __shfl_xor(ss, off);
  float rs = rsqrtf(ss * (1.0f / CM) + LN_EPS);

  float4 wv = ((const float4*)w)[lane];
  float4 bv = ((const float4*)b)[lane];
  unsigned p0 = pk_bf16(dx * rs * wv.x + bv.x, dy * rs * wv.y + bv.y);
  unsigned p1 = pk_bf16(dz * rs * wv.z + bv.z, dw * rs * wv.w + bv.w);
  uint2 u;
  u.x = p0;
  u.y = p1;
  *(uint2*)(mn + (size_t)row * CM + lane * 4) = u;
}

// ---------------------------------------------------------------------------
// Kernel 2: biasT[h][k][q] = (LN(z[q,k,:]) @ w_z)[h] * log2(e)   (transposed)
// ---------------------------------------------------------------------------
__global__ __launch_bounds__(128) void bias_kernel(
    const float* __restrict__ z, const float* __restrict__ w,
    const float* __restrict__ b, const float* __restrict__ wz,
    float* __restrict__ biasT) {
  int row = blockIdx.x;   // i*NR + j  (i = q, j = k)
  int t = threadIdx.x;    // 0..127
  __shared__ float red[2];
  __shared__ float zn[CZ];
  __shared__ float part[16][9];

  float x = z[(size_t)row * CZ + t];

  float v = x;
  #pragma unroll
  for (int off = 32; off; off >>= 1) v += __shfl_xor(v, off);
  if ((t & 63) == 0) red[t >> 6] = v;
  __syncthreads();
  float mu = (red[0] + red[1]) * (1.0f / CZ);
  float d = x - mu;
  __syncthreads();

  v = d * d;
  #pragma unroll
  for (int off = 32; off; off >>= 1) v += __shfl_xor(v, off);
  if ((t & 63) == 0) red[t >> 6] = v;
  __syncthreads();
  float var = (red[0] + red[1]) * (1.0f / CZ);

  zn[t] = d * rsqrtf(var + LN_EPS) * w[t] + b[t];
  __syncthreads();

  int h = t & 7, grp = t >> 3;
  float acc = 0.0f;
  #pragma unroll
  for (int cc = 0; cc < 8; ++cc) {
    int c = grp * 8 + cc;
    acc += zn[c] * wz[c * NH + h];
  }
  part[grp][h] = acc;
  __syncthreads();

  if (t < NH) {
    float s = 0.0f;
    #pragma unroll
    for (int g = 0; g < 16; ++g) s += part[g][t];
    int i = row >> 8, j = row & 255;
    biasT[(size_t)t * (NR * NR) + (size_t)j * NR + i] = s * LOG2E;
  }
}

// ---------------------------------------------------------------------------
// Kernel 3: fused q/k/v/g projections via MFMA, accumulator-resident form.
// Block = 4 waves sharing one 32-row A-tile (L1 reuse); wave = one matrix.
// kc is OUTER; acc[8] covers the full N=256 of the wave's matrix (128 VGPR,
// cannot be spilled) so A/B loads are short-lived streams.
// All outputs row-major coalesced (V transposed by a separate kernel).
// ---------------------------------------------------------------------------
__global__ __launch_bounds__(256, 2) void qkvg_mfma_kernel(
    const bf16* __restrict__ mn, const bf16* __restrict__ wp,
    const float* __restrict__ bg,
    bf16* __restrict__ qo, bf16* __restrict__ ko,
    bf16* __restrict__ vo, bf16* __restrict__ go) {
  int mat = threadIdx.x >> 6;  // wave id = matrix (q,k,v,g)
  int lane = threadIdx.x & 63;
  int lo = lane & 31, hi = lane >> 5;
  size_t m0 = (size_t)blockIdx.x * 32;

  const bf16* arow = mn + (m0 + lo) * 256 + hi * 8;
  const bf16* wbase = wp + (size_t)mat * 65536 + ((size_t)hi * 256 + lo) * 8;

  f32x16 acc[8] = {};
  #pragma unroll 2
  for (int kc = 0; kc < 16; ++kc) {
    short8 a = load8(arow + kc * 16);
    const bf16* wkc = wbase + (size_t)kc * 4096;
    #pragma unroll
    for (int nt = 0; nt < 8; ++nt) {
      short8 b = load8(wkc + nt * 256);
      acc[nt] = __builtin_amdgcn_mfma_f32_32x32x16_bf16(a, b, acc[nt], 0, 0, 0);
    }
  }

  bf16* outp = mat == 0 ? qo : mat == 1 ? ko : mat == 2 ? vo : go;
  if (mat == 3) {
    #pragma unroll
    for (int nt = 0; nt < 8; ++nt) {
      float bgv = bg[nt * 32 + lo];
      #pragma unroll
      for (int r = 0; r < 16; ++r) {
        int crow = (r & 3) + ((r >> 2) << 3) + (hi << 2);
        float sv = 1.0f / (1.0f + __expf(-(acc[nt][r] + bgv)));
        outp[(m0 + crow) * 256 + nt * 32 + lo] = __float2bfloat16(sv);
      }
    }
  } else {
    #pragma unroll
    for (int nt = 0; nt < 8; ++nt) {
      #pragma unroll
      for (int r = 0; r < 16; ++r) {
        int crow = (r & 3) + ((r >> 2) << 3) + (hi << 2);
        outp[(m0 + crow) * 256 + nt * 32 + lo] = __float2bfloat16(acc[nt][r]);
      }
    }
  }
}

// ---------------------------------------------------------------------------
// Kernel 3b: vT[s][h][c][k] = vo[s][k][h*32+c]. One block per (s,h), LDS tile,
// coalesced full-line reads and writes.
// ---------------------------------------------------------------------------
__global__ __launch_bounds__(256) void transpose_v_kernel(
    const bf16* __restrict__ vo, bf16* __restrict__ vT) {
  int s = blockIdx.x >> 3, h = blockIdx.x & 7;
  int t = threadIdx.x;
  __shared__ bf16 tile[256][40];  // stride 80 B (16B-aligned), conflict-light

  #pragma unroll
  for (int p = 0; p < 4; ++p) {
    int k = p * 64 + (t >> 2);
    int c0 = (t & 3) * 8;
    uint4 u = *(const uint4*)(vo + ((size_t)(s * 256 + k)) * 256 + h * 32 + c0);
    *(uint4*)&tile[k][c0] = u;
  }
  __syncthreads();

  int c = t >> 3, k0 = (t & 7) * 32;
  bf16 buf[32];
  #pragma unroll
  for (int j = 0; j < 32; ++j) buf[j] = tile[k0 + j][c];
  bf16* dst = vT + (((size_t)(s * 8 + h) * 32 + c) * 256 + k0);
  #pragma unroll
  for (int q = 0; q < 4; ++q)
    *(uint4*)(dst + q * 8) = *(const uint4*)(buf + q * 8);
}

// ---------------------------------------------------------------------------
// Kernel 4: MFMA attention, one wave per (s, h, 32-q tile). No LDS, no
// barriers. Swapped QK^T; V read from vT as direct B-frag load8.
// ---------------------------------------------------------------------------
__global__ __launch_bounds__(256, 2) void attn_mfma_kernel(
    const bf16* __restrict__ qb, const bf16* __restrict__ kb,
    const bf16* __restrict__ vT, const bf16* __restrict__ gb,
    const float* __restrict__ biasT, bf16* __restrict__ gob) {
  int wid = blockIdx.x * 4 + (threadIdx.x >> 6);
  int lane = threadIdx.x & 63;
  int lo = lane & 31;
  int hi = lane >> 5;
  int s = wid >> 6;
  int h = (wid >> 3) & 7;
  int q0 = (wid & 7) * 32;

  const size_t base = (size_t)s * NR * 256 + h * CH;

  short8 qf[2];
  #pragma unroll
  for (int cc = 0; cc < 2; ++cc)
    qf[cc] = load8(qb + base + (size_t)(q0 + lo) * 256 + cc * 16 + hi * 8);

  f32x16 acc[8];
  __builtin_amdgcn_s_setprio(1);
  #pragma unroll
  for (int t = 0; t < 8; ++t) {
    short8 kf0 = load8(kb + base + (size_t)(t * 32 + lo) * 256 + hi * 8);
    short8 kf1 = load8(kb + base + (size_t)(t * 32 + lo) * 256 + 16 + hi * 8);
    f32x16 z = {};
    acc[t] = __builtin_amdgcn_mfma_f32_32x32x16_bf16(kf0, qf[0], z, 0, 0, 0);
    acc[t] = __builtin_amdgcn_mfma_f32_32x32x16_bf16(kf1, qf[1], acc[t], 0, 0, 0);
  }
  __builtin_amdgcn_s_setprio(0);

  const float* bh = biasT + (size_t)h * (NR * NR) + q0 + lo;
  #pragma unroll
  for (int t = 0; t < 8; ++t) {
    #pragma unroll
    for (int r = 0; r < 16; ++r) {
      int kk = t * 32 + (r & 3) + ((r >> 2) << 3) + (hi << 2);
      acc[t][r] = fmaf(acc[t][r], SCALE2, bh[(size_t)kk * NR]);
    }
  }

  float mx = -3.0e38f;
  #pragma unroll
  for (int t = 0; t < 8; ++t)
    #pragma unroll
    for (int r = 0; r < 16; ++r) mx = fmaxf(mx, acc[t][r]);
  mx = fmaxf(mx, __shfl_xor(mx, 32));

  float l = 0.0f;
  #pragma unroll
  for (int t = 0; t < 8; ++t) {
    #pragma unroll
    for (int r = 0; r < 16; ++r) {
      float e = exp2f(acc[t][r] - mx);
      acc[t][r] = e;
      l += e;
    }
  }
  l += __shfl_xor(l, 32);

  f32x16 o = {};
  const bf16* vt = vT + ((size_t)(s * NH + h) * CH + lo) * 256;
  #pragma unroll
  for (int kc = 0; kc < 16; ++kc) {
    int t = kc >> 1;
    int rb = (kc & 1) << 3;
    unsigned uL0 = pk_bf16(acc[t][rb + 0], acc[t][rb + 1]);
    unsigned uL1 = pk_bf16(acc[t][rb + 2], acc[t][rb + 3]);
    unsigned uH0 = pk_bf16(acc[t][rb + 4], acc[t][rb + 5]);
    unsigned uH1 = pk_bf16(acc[t][rb + 6], acc[t][rb + 7]);
    unsigned sL0 = __shfl_xor(uL0, 32), sL1 = __shfl_xor(uL1, 32);
    unsigned sH0 = __shfl_xor(uH0, 32), sH1 = __shfl_xor(uH1, 32);
    uint4 pu;
    pu.x = hi ? sH0 : uL0;
    pu.y = hi ? sH1 : uL1;
    pu.z = hi ? uH0 : sL0;
    pu.w = hi ? uH1 : sL1;
    short8 pf = __builtin_bit_cast(short8, pu);
    short8 vf = load8(vt + kc * 16 + hi * 8);
    o = __builtin_amdgcn_mfma_f32_32x32x16_bf16(pf, vf, o, 0, 0, 0);
  }

  float linv = 1.0f / l;
  #pragma unroll
  for (int r = 0; r < 16; ++r) {
    int crow = (r & 3) + ((r >> 2) << 3) + (hi << 2);
    float li = __shfl(linv, crow);
    size_t idx = base + (size_t)(q0 + crow) * 256 + lo;
    float gg = __bfloat162float(gb[idx]);
    gob[idx] = __float2bfloat16(gg * o[r] * li);
  }
}

// ---------------------------------------------------------------------------
// Kernel 5: out = (g*o) @ w_o + b_o via MFMA, accumulator-resident form.
// ---------------------------------------------------------------------------
__global__ __launch_bounds__(256, 2) void out_mfma_kernel(
    const bf16* __restrict__ gob, const bf16* __restrict__ wop,
    const float* __restrict__ bo, float* __restrict__ out) {
  int wid = blockIdx.x * 4 + (threadIdx.x >> 6);
  int lane = threadIdx.x & 63;
  int lo = lane & 31, hi = lane >> 5;
  size_t m0 = (size_t)wid * 32;

  const bf16* arow = gob + (m0 + lo) * 256 + hi * 8;
  const bf16* wbase = wop + ((size_t)hi * 256 + lo) * 8;

  f32x16 acc[8] = {};
  #pragma unroll 2
  for (int kc = 0; kc < 16; ++kc) {
    short8 a = load8(arow + kc * 16);
    const bf16* wkc = wbase + (size_t)kc * 4096;
    #pragma unroll
    for (int nt = 0; nt < 8; ++nt) {
      short8 b = load8(wkc + nt * 256);
      acc[nt] = __builtin_amdgcn_mfma_f32_32x32x16_bf16(a, b, acc[nt], 0, 0, 0);
    }
  }

  #pragma unroll
  for (int nt = 0; nt < 8; ++nt) {
    float bv = bo[nt * 32 + lo];
    #pragma unroll
    for (int r = 0; r < 16; ++r) {
      int crow = (r & 3) + ((r >> 2) << 3) + (hi << 2);
      out[(m0 + crow) * 256 + nt * 32 + lo] = acc[nt][r] + bv;
    }
  }
}

// ---------------------------------------------------------------------------
extern "C" void kernel_launch(void* const* d_in, const int* in_sizes, int n_in,
                              void* d_out, int out_size, void* d_ws, size_t ws_size,
                              hipStream_t stream) {
  const float* m      = (const float*)d_in[0];
  const float* z      = (const float*)d_in[1];
  const float* ln_m_w = (const float*)d_in[2];
  const float* ln_m_b = (const float*)d_in[3];
  const float* ln_z_w = (const float*)d_in[4];
  const float* ln_z_b = (const float*)d_in[5];
  const float* w_z    = (const float*)d_in[6];
  const float* w_q    = (const float*)d_in[7];
  const float* w_k    = (const float*)d_in[8];
  const float* w_v    = (const float*)d_in[9];
  const float* w_g    = (const float*)d_in[10];
  const float* b_g    = (const float*)d_in[11];
  const float* w_o    = (const float*)d_in[12];
  const float* b_o    = (const float*)d_in[13];
  float* out = (float*)d_out;

  const size_t SZ = (size_t)NS * NR * 256;

  bf16* mn   = (bf16*)d_ws;
  bf16* qb   = mn + SZ;
  bf16* kb   = qb + SZ;
  bf16* vo   = kb + SZ;
  bf16* gb   = vo + SZ;
  bf16* gob  = gb + SZ;
  float* biasT = (float*)(gob + SZ);            // 2 MB
  bf16* wp   = (bf16*)(biasT + NH * NR * NR);   // 5*65536 bf16 = 640 KB
  bf16* wop  = wp + 4 * 65536;
  bf16* vT   = mn;  // mn is dead after qkvg; reuse its slot for vT

  pack_w_kernel<<<dim3(32, 5), 256, 0, stream>>>(w_q, w_k, w_v, w_g, w_o, wp);
  ln_m_kernel<<<(NS * NR) / 4, 256, 0, stream>>>(m, ln_m_w, ln_m_b, mn);
  bias_kernel<<<NR * NR, 128, 0, stream>>>(z, ln_z_w, ln_z_b, w_z, biasT);
  qkvg_mfma_kernel<<<(NS * NR) / 32, 256, 0, stream>>>(mn, wp, b_g,
                                                       qb, kb, vo, gb);
  transpose_v_kernel<<<NS * NH, 256, 0, stream>>>(vo, vT);
  attn_mfma_kernel<<<(NS * NH * 8) / 4, 256, 0, stream>>>(qb, kb, vT, gb,
                                                          biasT, gob);
  out_mfma_kernel<<<(NS * NR) / 32 / 4, 256, 0, stream>>>(gob, wop, b_o, out);
}